// Round 5
// baseline (2599.796 us; speedup 1.0000x reference)
//
#include <hip/hip_runtime.h>
#include <math.h>

#define NN 200000
#define NE 3200000
#define NF 128
#define NG 1000
#define KSEL 30
#define CCAT 97

#define BWID 256                  // nodes per bucket (dst >> 8)
#define NB 782                    // ceil(NN / BWID)
#define BCAP 4608                 // per-bucket edge capacity (mean 4092, sigma ~64)
#define P1_CHUNK 8192             // edges per block in partition pass
#define P1_BLKS 391               // ceil(NE / P1_CHUNK)

// ---------------- pass 1: partition edges into dst-buckets ----------------
// packed edge: src (18 bits) | local-dst (8 bits) << 18
__global__ void k_p1_partition(const int* __restrict__ ei, int* __restrict__ bcursor,
                               int* __restrict__ ebuf) {
    __shared__ int lhist[NB];
    __shared__ int lbase[NB];
    int tid = threadIdx.x;
    int base = blockIdx.x * P1_CHUNK;
    for (int b = tid; b < NB; b += 256) lhist[b] = 0;
    __syncthreads();
    for (int it = 0; it < P1_CHUNK / 256; it++) {
        int e = base + it * 256 + tid;
        if (e < NE) {
            int s = ei[e], d = ei[NE + e];
            if (s != d) atomicAdd(&lhist[d >> 8], 1);
        }
    }
    __syncthreads();
    for (int b = tid; b < NB; b += 256) {
        int cnt = lhist[b];
        lbase[b] = cnt ? atomicAdd(&bcursor[b], cnt) : 0;
        lhist[b] = 0;
    }
    __syncthreads();
    for (int it = 0; it < P1_CHUNK / 256; it++) {
        int e = base + it * 256 + tid;
        if (e < NE) {
            int s = ei[e], d = ei[NE + e];
            if (s != d) {
                int b = d >> 8;
                int r = atomicAdd(&lhist[b], 1);
                int pos = lbase[b] + r;
                if (pos >= BCAP) pos = BCAP - 1;  // defensive (cannot happen)
                ebuf[b * BCAP + pos] = s | ((d & 255) << 18);
            }
        }
    }
}

// ---------------- pass 2: per-bucket in-degree -> inv_sqrt ----------------
__global__ void k_p2(const int* __restrict__ bcursor, const int* __restrict__ ebuf,
                     float* __restrict__ inv_sqrt) {
    __shared__ int lcnt[BWID];
    int b = blockIdx.x;
    int tid = threadIdx.x;
    if (tid < BWID) lcnt[tid] = 0;
    __syncthreads();
    int size = bcursor[b];
    if (size > BCAP) size = BCAP;
    const int* eb = ebuf + (size_t)b * BCAP;
    for (int k = tid; k < size; k += 256) atomicAdd(&lcnt[eb[k] >> 18], 1);
    __syncthreads();
    if (tid < BWID) {
        int node = (b << 8) + tid;
        if (node < NN) inv_sqrt[node] = rsqrtf((float)(lcnt[tid] + 1));
    }
}

// ---------------- dense matmul: hws[n,32] = (X[n,K] @ W[K,32]) * inv_sqrt[n] ----------------
template <int K>
__global__ void k_mm(const float* __restrict__ X, const float* __restrict__ W,
                     const float* __restrict__ inv_sqrt, float* __restrict__ Y) {
    __shared__ float4 sW[K * 8];   // sW[k*8+q] = W[k][4q..4q+3]
    int tid = threadIdx.x;
    for (int i = tid; i < K * 8; i += 256) sW[i] = ((const float4*)W)[i];
    __syncthreads();
    int row = blockIdx.x * 256 + tid;
    if (row >= NN) return;
    float s = inv_sqrt[row];
    const float4* xp = (const float4*)(X + (size_t)row * K);
    float4 acc[8];
#pragma unroll
    for (int q = 0; q < 8; q++) acc[q] = make_float4(0.f, 0.f, 0.f, 0.f);
#pragma unroll 2
    for (int k4 = 0; k4 < K / 4; k4++) {
        float4 xv = xp[k4];
        const float4* wk = &sW[k4 * 32];
#pragma unroll
        for (int kk = 0; kk < 4; kk++) {
            float xs = (kk == 0) ? xv.x : (kk == 1) ? xv.y : (kk == 2) ? xv.z : xv.w;
#pragma unroll
            for (int q = 0; q < 8; q++) {
                float4 w = wk[kk * 8 + q];
                acc[q].x = fmaf(xs, w.x, acc[q].x);
                acc[q].y = fmaf(xs, w.y, acc[q].y);
                acc[q].z = fmaf(xs, w.z, acc[q].z);
                acc[q].w = fmaf(xs, w.w, acc[q].w);
            }
        }
    }
    float4* yp = (float4*)(Y + (size_t)row * 32);
#pragma unroll
    for (int q = 0; q < 8; q++) {
        float4 v = acc[q];
        v.x *= s; v.y *= s; v.z *= s; v.w *= s;
        yp[q] = v;
    }
}

// ---------------- edge-streaming aggregation, LDS accumulators, 32 ch ----------------
__global__ __launch_bounds__(256) void k_aggb(const int* __restrict__ bcursor,
                                              const int* __restrict__ ebuf,
                                              const float* __restrict__ hws,
                                              const float* __restrict__ inv_sqrt,
                                              const float* __restrict__ bias,
                                              float* __restrict__ xout) {
    __shared__ float acc[BWID * 32];   // 32 KB
    int b = blockIdx.x;
    int tid = threadIdx.x;
    int node0 = b << 8;
    int c = tid & 31;
    // init with self-loop term (coalesced); zero for OOB tail nodes
    for (int i = tid; i < BWID * 32; i += 256) {
        int node = node0 + (i >> 5);
        acc[i] = (node < NN) ? hws[(size_t)node * 32 + (i & 31)] : 0.0f;
    }
    __syncthreads();
    int size = bcursor[b];
    if (size > BCAP) size = BCAP;
    const int* eb = ebuf + (size_t)b * BCAP;
    int eidx = tid >> 5;               // 0..7: edge slot within group
    for (int base = 0; base < size; base += 32) {
#pragma unroll
        for (int u = 0; u < 4; u++) {
            int e = base + u * 8 + eidx;
            if (e < size) {
                int v = eb[e];
                int s = v & 0x3FFFF;
                int l = v >> 18;
                float val = hws[(size_t)s * 32 + c];
                atomicAdd(&acc[(l << 5) + c], val);
            }
        }
    }
    __syncthreads();
    for (int i = tid; i < BWID * 32; i += 256) {
        int node = node0 + (i >> 5);
        if (node < NN)
            xout[(size_t)node * 32 + (i & 31)] =
                tanhf(fmaf(acc[i], inv_sqrt[node], bias[i & 31]));
    }
}

// layer 4: hws4[n] = (x3[n,:] . W4) * inv_sqrt[n]
__global__ void k_mm4(const float* __restrict__ x3, const float* __restrict__ W4,
                      const float* __restrict__ inv_sqrt, float* __restrict__ hws4) {
    int n = blockIdx.x * 256 + threadIdx.x;
    if (n >= NN) return;
    const float4* xr = (const float4*)(x3 + (size_t)n * 32);
    float acc = 0.0f;
#pragma unroll
    for (int q = 0; q < 8; q++) {
        float4 v = xr[q];
        acc = fmaf(v.x, W4[q * 4 + 0], acc);
        acc = fmaf(v.y, W4[q * 4 + 1], acc);
        acc = fmaf(v.z, W4[q * 4 + 2], acc);
        acc = fmaf(v.w, W4[q * 4 + 3], acc);
    }
    hws4[n] = acc * inv_sqrt[n];
}

// layer-4 aggregation (1 channel)
__global__ void k_agg1b(const int* __restrict__ bcursor, const int* __restrict__ ebuf,
                        const float* __restrict__ hws4, const float* __restrict__ inv_sqrt,
                        const float* __restrict__ b4, float* __restrict__ x4) {
    __shared__ float acc[BWID];
    int b = blockIdx.x;
    int tid = threadIdx.x;
    int node0 = b << 8;
    if (tid < BWID) {
        int node = node0 + tid;
        acc[tid] = (node < NN) ? hws4[node] : 0.0f;
    }
    __syncthreads();
    int size = bcursor[b];
    if (size > BCAP) size = BCAP;
    const int* eb = ebuf + (size_t)b * BCAP;
    for (int e = tid; e < size; e += 256) {
        int v = eb[e];
        atomicAdd(&acc[v >> 18], hws4[v & 0x3FFFF]);
    }
    __syncthreads();
    if (tid < BWID) {
        int node = node0 + tid;
        if (node < NN) x4[node] = tanhf(fmaf(acc[tid], inv_sqrt[node], b4[0]));
    }
}

// ---------------- sort-pool ----------------
__global__ void k_hist(const int* __restrict__ batch, int* __restrict__ counts) {
    int n = blockIdx.x * 256 + threadIdx.x;
    if (n < NN) atomicAdd(&counts[batch[n]], 1);
}

__global__ void k_gscan(const int* __restrict__ counts, int* __restrict__ starts) {
    __shared__ int s[1024];
    int tid = threadIdx.x;
    int c = (tid < NG) ? counts[tid] : 0;
    s[tid] = c;
    __syncthreads();
    for (int off = 1; off < 1024; off <<= 1) {
        int v = s[tid];
        int a = (tid >= off) ? s[tid - off] : 0;
        __syncthreads();
        s[tid] = v + a;
        __syncthreads();
    }
    if (tid < NG) starts[tid] = s[tid] - c;
}

__global__ void k_sortpool(const int* __restrict__ starts, const int* __restrict__ counts,
                           const float* __restrict__ x1, const float* __restrict__ x2,
                           const float* __restrict__ x3, const float* __restrict__ x4,
                           float* __restrict__ pooled) {
    __shared__ float keys[1024];
    __shared__ int sel[KSEL];
    int g = blockIdx.x;
    int tid = threadIdx.x;
    int start = starts[g];
    int cnt = counts[g];
    if (cnt > 1024) cnt = 1024;
    for (int i = tid; i < cnt; i += 256) keys[i] = x4[start + i];
    __syncthreads();
    for (int i = tid; i < cnt; i += 256) {
        float ki = keys[i];
        int rank = 0;
        for (int j = 0; j < cnt; j++) {
            float kj = keys[j];
            rank += (kj > ki) || (kj == ki && j < i);  // stable desc, matches lexsort
        }
        if (rank < KSEL) sel[rank] = start + i;
    }
    __syncthreads();
    int selcnt = cnt < KSEL ? cnt : KSEL;
    for (int t = tid; t < KSEL * CCAT; t += 256) {
        int r = t / CCAT, ch = t - r * CCAT;
        float v = 0.0f;
        if (r < selcnt) {
            int node = sel[r];
            if (ch < 32)      v = x1[(size_t)node * 32 + ch];
            else if (ch < 64) v = x2[(size_t)node * 32 + ch - 32];
            else if (ch < 96) v = x3[(size_t)node * 32 + ch - 64];
            else              v = x4[node];
        }
        pooled[g * (KSEL * CCAT) + t] = v;
    }
}

// ---------------- CNN + MLP head, one block per graph ----------------
__global__ void k_head(const float* __restrict__ pooled,
                       const float* __restrict__ w5, const float* __restrict__ b5,
                       const float* __restrict__ w6, const float* __restrict__ b6,
                       const float* __restrict__ fw1, const float* __restrict__ fb1,
                       const float* __restrict__ fw2, const float* __restrict__ fb2,
                       float* __restrict__ out) {
    __shared__ float sP[KSEL * CCAT];
    __shared__ float s5[16 * 30];
    __shared__ float smp[16 * 15];
    __shared__ float sz[352];
    __shared__ float sh[128];
    __shared__ float sl[10];
    int g = blockIdx.x;
    int tid = threadIdx.x;
    for (int i = tid; i < KSEL * CCAT; i += 256) sP[i] = pooled[g * (KSEL * CCAT) + i];
    __syncthreads();
    for (int t = tid; t < 16 * 30; t += 256) {
        int c = t / 30, j = t - c * 30;
        float acc = b5[c];
        for (int i = 0; i < CCAT; i++) acc = fmaf(sP[j * CCAT + i], w5[c * CCAT + i], acc);
        s5[c * 30 + j] = fmaxf(acc, 0.0f);
    }
    __syncthreads();
    for (int t = tid; t < 16 * 15; t += 256) {
        int c = t / 15, j = t - c * 15;
        smp[t] = fmaxf(s5[c * 30 + 2 * j], s5[c * 30 + 2 * j + 1]);
    }
    __syncthreads();
    for (int t = tid; t < 32 * 11; t += 256) {
        int c = t / 11, j = t - c * 11;
        float acc = b6[c];
        for (int ci = 0; ci < 16; ci++) {
#pragma unroll
            for (int k = 0; k < 5; k++)
                acc = fmaf(smp[ci * 15 + j + k], w6[(c * 16 + ci) * 5 + k], acc);
        }
        sz[t] = fmaxf(acc, 0.0f);
    }
    __syncthreads();
    if (tid < 128) {
        float acc = fb1[tid];
        for (int i = 0; i < 352; i++) acc = fmaf(sz[i], fw1[i * 128 + tid], acc);
        sh[tid] = fmaxf(acc, 0.0f);
    }
    __syncthreads();
    if (tid < 10) {
        float acc = fb2[tid];
        for (int i = 0; i < 128; i++) acc = fmaf(sh[i], fw2[i * 10 + tid], acc);
        sl[tid] = acc;
    }
    __syncthreads();
    if (tid < 10) {
        float m = -1e30f;
        for (int i = 0; i < 10; i++) m = fmaxf(m, sl[i]);
        float ssum = 0.0f;
        for (int i = 0; i < 10; i++) ssum += expf(sl[i] - m);
        out[g * 10 + tid] = sl[tid] - m - logf(ssum);
    }
}

extern "C" void kernel_launch(void* const* d_in, const int* in_sizes, int n_in,
                              void* d_out, int out_size, void* d_ws, size_t ws_size,
                              hipStream_t stream) {
    const float* x   = (const float*)d_in[0];
    const int*   ei  = (const int*)d_in[1];
    const int*   bat = (const int*)d_in[2];
    const float* W1  = (const float*)d_in[3];
    const float* b1  = (const float*)d_in[4];
    const float* W2  = (const float*)d_in[5];
    const float* b2  = (const float*)d_in[6];
    const float* W3  = (const float*)d_in[7];
    const float* b3  = (const float*)d_in[8];
    const float* W4  = (const float*)d_in[9];
    const float* b4  = (const float*)d_in[10];
    const float* w5  = (const float*)d_in[11];
    const float* b5  = (const float*)d_in[12];
    const float* w6  = (const float*)d_in[13];
    const float* b6  = (const float*)d_in[14];
    const float* fw1 = (const float*)d_in[15];
    const float* fb1 = (const float*)d_in[16];
    const float* fw2 = (const float*)d_in[17];
    const float* fb2 = (const float*)d_in[18];
    float* out = (float*)d_out;

    float* ws = (float*)d_ws;
    float* inv_sqrt = ws;                          // NN
    float* hws      = inv_sqrt + NN;               // NN*32 (also hws4 in first NN)
    float* x1       = hws + (size_t)NN * 32;       // NN*32
    float* x2       = x1 + (size_t)NN * 32;        // NN*32
    float* x3       = x2 + (size_t)NN * 32;        // NN*32
    float* x4       = x3 + (size_t)NN * 32;        // NN
    float* pooled   = x4 + NN;                     // NG*KSEL*CCAT
    int* ebuf       = (int*)(pooled + NG * KSEL * CCAT);  // NB*BCAP (~14.4 MB)
    int* bcursor    = ebuf + (size_t)NB * BCAP;    // NB (pad to 1024)
    int* gcounts    = bcursor + 1024;              // 1024
    int* gstarts    = gcounts + 1024;              // 1024

    const int TB = 256;
    int gN = (NN + TB - 1) / TB;

    // ---- bucket partition (one-time) ----
    hipMemsetAsync(bcursor, 0, 1024 * sizeof(int), stream);
    k_p1_partition<<<P1_BLKS, TB, 0, stream>>>(ei, bcursor, ebuf);
    k_p2<<<NB, TB, 0, stream>>>(bcursor, ebuf, inv_sqrt);

    // ---- graph histogram/offsets (independent) ----
    hipMemsetAsync(gcounts, 0, 1024 * sizeof(int), stream);
    k_hist<<<gN, TB, 0, stream>>>(bat, gcounts);
    k_gscan<<<1, 1024, 0, stream>>>(gcounts, gstarts);

    // ---- GCN layers ----
    k_mm<128><<<gN, TB, 0, stream>>>(x, W1, inv_sqrt, hws);
    k_aggb<<<NB, TB, 0, stream>>>(bcursor, ebuf, hws, inv_sqrt, b1, x1);
    k_mm<32><<<gN, TB, 0, stream>>>(x1, W2, inv_sqrt, hws);
    k_aggb<<<NB, TB, 0, stream>>>(bcursor, ebuf, hws, inv_sqrt, b2, x2);
    k_mm<32><<<gN, TB, 0, stream>>>(x2, W3, inv_sqrt, hws);
    k_aggb<<<NB, TB, 0, stream>>>(bcursor, ebuf, hws, inv_sqrt, b3, x3);
    k_mm4<<<gN, TB, 0, stream>>>(x3, W4, inv_sqrt, hws);
    k_agg1b<<<NB, TB, 0, stream>>>(bcursor, ebuf, hws, inv_sqrt, b4, x4);

    // ---- sort-pool + head ----
    k_sortpool<<<NG, TB, 0, stream>>>(gstarts, gcounts, x1, x2, x3, x4, pooled);
    k_head<<<NG, TB, 0, stream>>>(pooled, w5, b5, w6, b6, fw1, fb1, fw2, fb2, out);
}

// Round 6
// 701.393 us; speedup vs baseline: 3.7066x; 3.7066x over previous
//
#include <hip/hip_runtime.h>
#include <math.h>

#define NN 200000
#define NE 3200000
#define NF 128
#define NG 1000
#define KSEL 30
#define CCAT 97
#define NPAD 200704      // 196 * 1024, padded node count for the scan
#define SCAN_BLKS 196

#define BWID 512                  // nodes per bucket (dst >> 9)
#define NB 391                    // ceil(NN / BWID)
#define BCAP 10240                // per-bucket edge capacity (mean 8184, sigma ~90)
#define P1_CHUNK 8192             // edges per block in partition pass
#define P1_BLKS 391               // ceil(NE / P1_CHUNK)

// ---------------- pass 1: partition edges into dst-buckets ----------------
__global__ void k_p1_partition(const int* __restrict__ ei, int* __restrict__ bcursor,
                               int* __restrict__ ebuf) {
    __shared__ int lhist[NB];
    __shared__ int lbase[NB];
    int tid = threadIdx.x;
    int base = blockIdx.x * P1_CHUNK;
    for (int b = tid; b < NB; b += 256) lhist[b] = 0;
    __syncthreads();
    for (int it = 0; it < P1_CHUNK / 256; it++) {
        int e = base + it * 256 + tid;
        if (e < NE) {
            int s = ei[e], d = ei[NE + e];
            if (s != d) atomicAdd(&lhist[d >> 9], 1);
        }
    }
    __syncthreads();
    for (int b = tid; b < NB; b += 256) {
        int cnt = lhist[b];
        lbase[b] = cnt ? atomicAdd(&bcursor[b], cnt) : 0;
        lhist[b] = 0;
    }
    __syncthreads();
    for (int it = 0; it < P1_CHUNK / 256; it++) {
        int e = base + it * 256 + tid;
        if (e < NE) {
            int s = ei[e], d = ei[NE + e];
            if (s != d) {
                int b = d >> 9;
                int r = atomicAdd(&lhist[b], 1);
                int pos = lbase[b] + r;
                if (pos >= BCAP) pos = BCAP - 1;  // defensive (cannot happen)
                ebuf[b * BCAP + pos] = s | ((d & 511) << 18);
            }
        }
    }
}

// ---------------- pass 2: per-bucket node counts (coalesced) + inv_sqrt ----------------
__global__ void k_p2_count(const int* __restrict__ bcursor, const int* __restrict__ ebuf,
                           int* __restrict__ rowcnt, float* __restrict__ inv_sqrt) {
    __shared__ int lcnt[BWID];
    int b = blockIdx.x;
    int tid = threadIdx.x;
    for (int i = tid; i < BWID; i += 256) lcnt[i] = 0;
    __syncthreads();
    int size = bcursor[b];
    if (size > BCAP) size = BCAP;
    const int* eb = ebuf + b * BCAP;
    for (int k = tid; k < size; k += 256) atomicAdd(&lcnt[eb[k] >> 18], 1);
    __syncthreads();
    int node0 = b * BWID;
    for (int i = tid; i < BWID; i += 256) {
        int node = node0 + i;
        if (node < NN) {
            int c = lcnt[i];
            rowcnt[node] = c;
            inv_sqrt[node] = rsqrtf((float)(c + 1));
        }
    }
}

// ---------------- scan (rowcnt -> rowstart, exclusive) ----------------
__global__ void k_scanA(const int* __restrict__ in, int* __restrict__ out,
                        int* __restrict__ bsums) {
    __shared__ int s[1024];
    int tid = threadIdx.x;
    int gid = blockIdx.x * 1024 + tid;
    int v = in[gid];
    s[tid] = v;
    __syncthreads();
    for (int off = 1; off < 1024; off <<= 1) {
        int a = (tid >= off) ? s[tid - off] : 0;
        int cur = s[tid];
        __syncthreads();
        s[tid] = cur + a;
        __syncthreads();
    }
    out[gid] = s[tid] - v;
    if (tid == 1023) bsums[blockIdx.x] = s[tid];
}

__global__ void k_scanB(int* __restrict__ bsums) {
    __shared__ int s[256];
    int tid = threadIdx.x;
    int v = (tid < SCAN_BLKS) ? bsums[tid] : 0;
    s[tid] = v;
    __syncthreads();
    for (int off = 1; off < 256; off <<= 1) {
        int a = (tid >= off) ? s[tid - off] : 0;
        int cur = s[tid];
        __syncthreads();
        s[tid] = cur + a;
        __syncthreads();
    }
    if (tid < SCAN_BLKS) bsums[tid] = s[tid] - v;
}

__global__ void k_scanC(int* __restrict__ out, const int* __restrict__ bsums) {
    int gid = blockIdx.x * 1024 + threadIdx.x;
    out[gid] += bsums[blockIdx.x];
}

// ---------------- pass 3: bucket -> CSR esrc (writes localized per block) ----------------
__global__ void k_p3_scatter(const int* __restrict__ bcursor, const int* __restrict__ ebuf,
                             const int* __restrict__ rowstart, int* __restrict__ esrc) {
    __shared__ int lcur[BWID];
    int b = blockIdx.x;
    int tid = threadIdx.x;
    int node0 = b * BWID;
    for (int i = tid; i < BWID; i += 256) lcur[i] = rowstart[node0 + i];
    __syncthreads();
    int size = bcursor[b];
    if (size > BCAP) size = BCAP;
    const int* eb = ebuf + b * BCAP;
    for (int k = tid; k < size; k += 256) {
        int v = eb[k];
        int local = v >> 18;
        int pos = atomicAdd(&lcur[local], 1);
        esrc[pos] = v & 0x3FFFF;
    }
}

// ---------------- dense matmul: hws[n,32] = (X[n,K] @ W[K,32]) * inv_sqrt[n] ----------------
template <int K>
__global__ void k_mm(const float* __restrict__ X, const float* __restrict__ W,
                     const float* __restrict__ inv_sqrt, float* __restrict__ Y) {
    __shared__ float4 sW[K * 8];   // sW[k*8+q] = W[k][4q..4q+3]
    int tid = threadIdx.x;
    for (int i = tid; i < K * 8; i += 256) sW[i] = ((const float4*)W)[i];
    __syncthreads();
    int row = blockIdx.x * 256 + tid;
    if (row >= NN) return;
    float s = inv_sqrt[row];
    const float4* xp = (const float4*)(X + (size_t)row * K);
    float4 acc[8];
#pragma unroll
    for (int q = 0; q < 8; q++) acc[q] = make_float4(0.f, 0.f, 0.f, 0.f);
#pragma unroll 2
    for (int k4 = 0; k4 < K / 4; k4++) {
        float4 xv = xp[k4];
        const float4* wk = &sW[k4 * 32];
#pragma unroll
        for (int kk = 0; kk < 4; kk++) {
            float xs = (kk == 0) ? xv.x : (kk == 1) ? xv.y : (kk == 2) ? xv.z : xv.w;
#pragma unroll
            for (int q = 0; q < 8; q++) {
                float4 w = wk[kk * 8 + q];
                acc[q].x = fmaf(xs, w.x, acc[q].x);
                acc[q].y = fmaf(xs, w.y, acc[q].y);
                acc[q].z = fmaf(xs, w.z, acc[q].z);
                acc[q].w = fmaf(xs, w.w, acc[q].w);
            }
        }
    }
    float4* yp = (float4*)(Y + (size_t)row * 32);
#pragma unroll
    for (int q = 0; q < 8; q++) {
        float4 v = acc[q];
        v.x *= s; v.y *= s; v.z *= s; v.w *= s;
        yp[q] = v;
    }
}

// ---------------- gather-aggregate, 8-wide ILP, 32 channels/node ----------------
__global__ void k_aggr(const int* __restrict__ rowstart, const int* __restrict__ esrc,
                       const float* __restrict__ hws, const float* __restrict__ inv_sqrt,
                       const float* __restrict__ b, float* __restrict__ xout) {
    int t = blockIdx.x * 256 + threadIdx.x;
    int n = t >> 5, c = t & 31;
    if (n >= NN) return;
    int e0 = rowstart[n], e1 = rowstart[n + 1];
    float a[8];
    a[0] = hws[(size_t)n * 32 + c];
#pragma unroll
    for (int k = 1; k < 8; k++) a[k] = 0.0f;
    for (int e = e0; e < e1; e += 8) {
        int ss[8];
#pragma unroll
        for (int k = 0; k < 8; k++) ss[k] = esrc[(e + k < e1) ? e + k : e];
        float vv[8];
#pragma unroll
        for (int k = 0; k < 8; k++) vv[k] = hws[(size_t)ss[k] * 32 + c];
        a[0] += vv[0];
#pragma unroll
        for (int k = 1; k < 8; k++) a[k] += (e + k < e1) ? vv[k] : 0.0f;
    }
    float acc = ((a[0] + a[1]) + (a[2] + a[3])) + ((a[4] + a[5]) + (a[6] + a[7]));
    xout[t] = tanhf(fmaf(acc, inv_sqrt[n], b[c]));
}

// layer 4: hws4[n] = (x3[n,:] . W4) * inv_sqrt[n]
__global__ void k_mm4(const float* __restrict__ x3, const float* __restrict__ W4,
                      const float* __restrict__ inv_sqrt, float* __restrict__ hws4) {
    int n = blockIdx.x * 256 + threadIdx.x;
    if (n >= NN) return;
    const float4* xr = (const float4*)(x3 + (size_t)n * 32);
    float acc = 0.0f;
#pragma unroll
    for (int q = 0; q < 8; q++) {
        float4 v = xr[q];
        acc = fmaf(v.x, W4[q * 4 + 0], acc);
        acc = fmaf(v.y, W4[q * 4 + 1], acc);
        acc = fmaf(v.z, W4[q * 4 + 2], acc);
        acc = fmaf(v.w, W4[q * 4 + 3], acc);
    }
    hws4[n] = acc * inv_sqrt[n];
}

// layer-4 aggregation (1 channel), 8-wide ILP
__global__ void k_aggr1(const int* __restrict__ rowstart, const int* __restrict__ esrc,
                        const float* __restrict__ hws4, const float* __restrict__ inv_sqrt,
                        const float* __restrict__ b4, float* __restrict__ x4) {
    int n = blockIdx.x * 256 + threadIdx.x;
    if (n >= NN) return;
    int e0 = rowstart[n], e1 = rowstart[n + 1];
    float a[8];
    a[0] = hws4[n];
#pragma unroll
    for (int k = 1; k < 8; k++) a[k] = 0.0f;
    for (int e = e0; e < e1; e += 8) {
        int ss[8];
#pragma unroll
        for (int k = 0; k < 8; k++) ss[k] = esrc[(e + k < e1) ? e + k : e];
        float vv[8];
#pragma unroll
        for (int k = 0; k < 8; k++) vv[k] = hws4[ss[k]];
        a[0] += vv[0];
#pragma unroll
        for (int k = 1; k < 8; k++) a[k] += (e + k < e1) ? vv[k] : 0.0f;
    }
    float acc = ((a[0] + a[1]) + (a[2] + a[3])) + ((a[4] + a[5]) + (a[6] + a[7]));
    x4[n] = tanhf(fmaf(acc, inv_sqrt[n], b4[0]));
}

// ---------------- sort-pool ----------------
__global__ void k_hist(const int* __restrict__ batch, int* __restrict__ counts) {
    int n = blockIdx.x * 256 + threadIdx.x;
    if (n < NN) atomicAdd(&counts[batch[n]], 1);
}

__global__ void k_gscan(const int* __restrict__ counts, int* __restrict__ starts) {
    __shared__ int s[1024];
    int tid = threadIdx.x;
    int c = (tid < NG) ? counts[tid] : 0;
    s[tid] = c;
    __syncthreads();
    for (int off = 1; off < 1024; off <<= 1) {
        int v = s[tid];
        int a = (tid >= off) ? s[tid - off] : 0;
        __syncthreads();
        s[tid] = v + a;
        __syncthreads();
    }
    if (tid < NG) starts[tid] = s[tid] - c;
}

__global__ void k_sortpool(const int* __restrict__ starts, const int* __restrict__ counts,
                           const float* __restrict__ x1, const float* __restrict__ x2,
                           const float* __restrict__ x3, const float* __restrict__ x4,
                           float* __restrict__ pooled) {
    __shared__ float keys[1024];
    __shared__ int sel[KSEL];
    int g = blockIdx.x;
    int tid = threadIdx.x;
    int start = starts[g];
    int cnt = counts[g];
    if (cnt > 1024) cnt = 1024;
    for (int i = tid; i < cnt; i += 256) keys[i] = x4[start + i];
    __syncthreads();
    for (int i = tid; i < cnt; i += 256) {
        float ki = keys[i];
        int rank = 0;
        for (int j = 0; j < cnt; j++) {
            float kj = keys[j];
            rank += (kj > ki) || (kj == ki && j < i);  // stable desc, matches lexsort
        }
        if (rank < KSEL) sel[rank] = start + i;
    }
    __syncthreads();
    int selcnt = cnt < KSEL ? cnt : KSEL;
    for (int t = tid; t < KSEL * CCAT; t += 256) {
        int r = t / CCAT, ch = t - r * CCAT;
        float v = 0.0f;
        if (r < selcnt) {
            int node = sel[r];
            if (ch < 32)      v = x1[(size_t)node * 32 + ch];
            else if (ch < 64) v = x2[(size_t)node * 32 + ch - 32];
            else if (ch < 96) v = x3[(size_t)node * 32 + ch - 64];
            else              v = x4[node];
        }
        pooled[g * (KSEL * CCAT) + t] = v;
    }
}

// ---------------- CNN + MLP head, one block per graph ----------------
__global__ void k_head(const float* __restrict__ pooled,
                       const float* __restrict__ w5, const float* __restrict__ b5,
                       const float* __restrict__ w6, const float* __restrict__ b6,
                       const float* __restrict__ fw1, const float* __restrict__ fb1,
                       const float* __restrict__ fw2, const float* __restrict__ fb2,
                       float* __restrict__ out) {
    __shared__ float sP[KSEL * CCAT];
    __shared__ float s5[16 * 30];
    __shared__ float smp[16 * 15];
    __shared__ float sz[352];
    __shared__ float sh[128];
    __shared__ float sl[10];
    int g = blockIdx.x;
    int tid = threadIdx.x;
    for (int i = tid; i < KSEL * CCAT; i += 256) sP[i] = pooled[g * (KSEL * CCAT) + i];
    __syncthreads();
    for (int t = tid; t < 16 * 30; t += 256) {
        int c = t / 30, j = t - c * 30;
        float acc = b5[c];
        for (int i = 0; i < CCAT; i++) acc = fmaf(sP[j * CCAT + i], w5[c * CCAT + i], acc);
        s5[c * 30 + j] = fmaxf(acc, 0.0f);
    }
    __syncthreads();
    for (int t = tid; t < 16 * 15; t += 256) {
        int c = t / 15, j = t - c * 15;
        smp[t] = fmaxf(s5[c * 30 + 2 * j], s5[c * 30 + 2 * j + 1]);
    }
    __syncthreads();
    for (int t = tid; t < 32 * 11; t += 256) {
        int c = t / 11, j = t - c * 11;
        float acc = b6[c];
        for (int ci = 0; ci < 16; ci++) {
#pragma unroll
            for (int k = 0; k < 5; k++)
                acc = fmaf(smp[ci * 15 + j + k], w6[(c * 16 + ci) * 5 + k], acc);
        }
        sz[t] = fmaxf(acc, 0.0f);
    }
    __syncthreads();
    if (tid < 128) {
        float acc = fb1[tid];
        for (int i = 0; i < 352; i++) acc = fmaf(sz[i], fw1[i * 128 + tid], acc);
        sh[tid] = fmaxf(acc, 0.0f);
    }
    __syncthreads();
    if (tid < 10) {
        float acc = fb2[tid];
        for (int i = 0; i < 128; i++) acc = fmaf(sh[i], fw2[i * 10 + tid], acc);
        sl[tid] = acc;
    }
    __syncthreads();
    if (tid < 10) {
        float m = -1e30f;
        for (int i = 0; i < 10; i++) m = fmaxf(m, sl[i]);
        float ssum = 0.0f;
        for (int i = 0; i < 10; i++) ssum += expf(sl[i] - m);
        out[g * 10 + tid] = sl[tid] - m - logf(ssum);
    }
}

extern "C" void kernel_launch(void* const* d_in, const int* in_sizes, int n_in,
                              void* d_out, int out_size, void* d_ws, size_t ws_size,
                              hipStream_t stream) {
    const float* x   = (const float*)d_in[0];
    const int*   ei  = (const int*)d_in[1];
    const int*   bat = (const int*)d_in[2];
    const float* W1  = (const float*)d_in[3];
    const float* b1  = (const float*)d_in[4];
    const float* W2  = (const float*)d_in[5];
    const float* b2  = (const float*)d_in[6];
    const float* W3  = (const float*)d_in[7];
    const float* b3  = (const float*)d_in[8];
    const float* W4  = (const float*)d_in[9];
    const float* b4  = (const float*)d_in[10];
    const float* w5  = (const float*)d_in[11];
    const float* b5  = (const float*)d_in[12];
    const float* w6  = (const float*)d_in[13];
    const float* b6  = (const float*)d_in[14];
    const float* fw1 = (const float*)d_in[15];
    const float* fb1 = (const float*)d_in[16];
    const float* fw2 = (const float*)d_in[17];
    const float* fb2 = (const float*)d_in[18];
    float* out = (float*)d_out;

    float* ws = (float*)d_ws;
    float* inv_sqrt = ws;                          // NN
    float* hws      = inv_sqrt + NN;               // NN*32 (also hws4 in first NN)
    float* x1       = hws + (size_t)NN * 32;       // NN*32
    float* x2       = x1 + (size_t)NN * 32;        // NN*32
    float* x3       = x2 + (size_t)NN * 32;        // NN*32
    float* x4       = x3 + (size_t)NN * 32;        // NN
    float* pooled   = x4 + NN;                     // NG*KSEL*CCAT
    int* rowcnt     = (int*)(pooled + NG * KSEL * CCAT);  // NPAD
    int* rowstart   = rowcnt + NPAD;               // NPAD
    int* esrc       = rowstart + NPAD;             // NE
    int* bcursor    = esrc + NE;                   // NB (pad to 512)
    int* bsums      = bcursor + 512;               // 256
    int* gcounts    = bsums + 256;                 // 1024
    int* gstarts    = gcounts + 1024;              // 1024
    int* ebuf       = (int*)x3;                    // NB*BCAP ints (16 MB), dead before x3 written

    const int TB = 256;
    int gN  = (NN + TB - 1) / TB;
    int gNC = (NN * 32 + TB - 1) / TB;

    // ---- CSR build via bucketed partition ----
    hipMemsetAsync(bcursor, 0, 512 * sizeof(int), stream);
    hipMemsetAsync(rowcnt, 0, NPAD * sizeof(int), stream);
    k_p1_partition<<<P1_BLKS, TB, 0, stream>>>(ei, bcursor, ebuf);
    k_p2_count<<<NB, TB, 0, stream>>>(bcursor, ebuf, rowcnt, inv_sqrt);
    k_scanA<<<SCAN_BLKS, 1024, 0, stream>>>(rowcnt, rowstart, bsums);
    k_scanB<<<1, 256, 0, stream>>>(bsums);
    k_scanC<<<SCAN_BLKS, 1024, 0, stream>>>(rowstart, bsums);
    k_p3_scatter<<<NB, TB, 0, stream>>>(bcursor, ebuf, rowstart, esrc);

    // ---- graph histogram/offsets (independent) ----
    hipMemsetAsync(gcounts, 0, 1024 * sizeof(int), stream);
    k_hist<<<gN, TB, 0, stream>>>(bat, gcounts);
    k_gscan<<<1, 1024, 0, stream>>>(gcounts, gstarts);

    // ---- GCN layers ----
    k_mm<128><<<gN, TB, 0, stream>>>(x, W1, inv_sqrt, hws);
    k_aggr<<<gNC, TB, 0, stream>>>(rowstart, esrc, hws, inv_sqrt, b1, x1);
    k_mm<32><<<gN, TB, 0, stream>>>(x1, W2, inv_sqrt, hws);
    k_aggr<<<gNC, TB, 0, stream>>>(rowstart, esrc, hws, inv_sqrt, b2, x2);
    k_mm<32><<<gN, TB, 0, stream>>>(x2, W3, inv_sqrt, hws);
    k_aggr<<<gNC, TB, 0, stream>>>(rowstart, esrc, hws, inv_sqrt, b3, x3);
    k_mm4<<<gN, TB, 0, stream>>>(x3, W4, inv_sqrt, hws);
    k_aggr1<<<gN, TB, 0, stream>>>(rowstart, esrc, hws, inv_sqrt, b4, x4);

    // ---- sort-pool + head ----
    k_sortpool<<<NG, TB, 0, stream>>>(gstarts, gcounts, x1, x2, x3, x4, pooled);
    k_head<<<NG, TB, 0, stream>>>(pooled, w5, b5, w6, b6, fw1, fb1, fw2, fb2, out);
}

// Round 7
// 610.293 us; speedup vs baseline: 4.2599x; 1.1493x over previous
//
#include <hip/hip_runtime.h>
#include <math.h>

#define NN 200000
#define NE 3200000
#define NF 128
#define NG 1000
#define KSEL 30
#define CCAT 97
#define NPAD 200704      // 196 * 1024, padded node count for the scan
#define SCAN_BLKS 196

#define BWID 512                  // nodes per bucket (dst >> 9)
#define NB 391                    // ceil(NN / BWID)
#define BCAP 10240                // per-bucket edge capacity (mean 8184, sigma ~90)
#define P1_CHUNK 8192             // edges per block in partition pass
#define P1_BLKS 391               // ceil(NE / P1_CHUNK)

// ---------------- pass 1: partition edges into dst-buckets ----------------
__global__ void k_p1_partition(const int* __restrict__ ei, int* __restrict__ bcursor,
                               int* __restrict__ ebuf) {
    __shared__ int lhist[NB];
    __shared__ int lbase[NB];
    int tid = threadIdx.x;
    int base = blockIdx.x * P1_CHUNK;
    for (int b = tid; b < NB; b += 256) lhist[b] = 0;
    __syncthreads();
    for (int it = 0; it < P1_CHUNK / 256; it++) {
        int e = base + it * 256 + tid;
        if (e < NE) {
            int s = ei[e], d = ei[NE + e];
            if (s != d) atomicAdd(&lhist[d >> 9], 1);
        }
    }
    __syncthreads();
    for (int b = tid; b < NB; b += 256) {
        int cnt = lhist[b];
        lbase[b] = cnt ? atomicAdd(&bcursor[b], cnt) : 0;
        lhist[b] = 0;
    }
    __syncthreads();
    for (int it = 0; it < P1_CHUNK / 256; it++) {
        int e = base + it * 256 + tid;
        if (e < NE) {
            int s = ei[e], d = ei[NE + e];
            if (s != d) {
                int b = d >> 9;
                int r = atomicAdd(&lhist[b], 1);
                int pos = lbase[b] + r;
                if (pos >= BCAP) pos = BCAP - 1;  // defensive (cannot happen)
                ebuf[b * BCAP + pos] = s | ((d & 511) << 18);
            }
        }
    }
}

// ---------------- pass 2: per-bucket node counts (coalesced) + inv_sqrt ----------------
__global__ void k_p2_count(const int* __restrict__ bcursor, const int* __restrict__ ebuf,
                           int* __restrict__ rowcnt, float* __restrict__ inv_sqrt) {
    __shared__ int lcnt[BWID];
    int b = blockIdx.x;
    int tid = threadIdx.x;
    for (int i = tid; i < BWID; i += 256) lcnt[i] = 0;
    __syncthreads();
    int size = bcursor[b];
    if (size > BCAP) size = BCAP;
    const int* eb = ebuf + b * BCAP;
    for (int k = tid; k < size; k += 256) atomicAdd(&lcnt[eb[k] >> 18], 1);
    __syncthreads();
    int node0 = b * BWID;
    for (int i = tid; i < BWID; i += 256) {
        int node = node0 + i;
        if (node < NN) {
            int c = lcnt[i];
            rowcnt[node] = c;
            inv_sqrt[node] = rsqrtf((float)(c + 1));
        }
    }
}

// ---------------- scan (rowcnt -> rowstart, exclusive) ----------------
__global__ void k_scanA(const int* __restrict__ in, int* __restrict__ out,
                        int* __restrict__ bsums) {
    __shared__ int s[1024];
    int tid = threadIdx.x;
    int gid = blockIdx.x * 1024 + tid;
    int v = in[gid];
    s[tid] = v;
    __syncthreads();
    for (int off = 1; off < 1024; off <<= 1) {
        int a = (tid >= off) ? s[tid - off] : 0;
        int cur = s[tid];
        __syncthreads();
        s[tid] = cur + a;
        __syncthreads();
    }
    out[gid] = s[tid] - v;
    if (tid == 1023) bsums[blockIdx.x] = s[tid];
}

__global__ void k_scanB(int* __restrict__ bsums) {
    __shared__ int s[256];
    int tid = threadIdx.x;
    int v = (tid < SCAN_BLKS) ? bsums[tid] : 0;
    s[tid] = v;
    __syncthreads();
    for (int off = 1; off < 256; off <<= 1) {
        int a = (tid >= off) ? s[tid - off] : 0;
        int cur = s[tid];
        __syncthreads();
        s[tid] = cur + a;
        __syncthreads();
    }
    if (tid < SCAN_BLKS) bsums[tid] = s[tid] - v;
}

__global__ void k_scanC(int* __restrict__ out, const int* __restrict__ bsums) {
    int gid = blockIdx.x * 1024 + threadIdx.x;
    out[gid] += bsums[blockIdx.x];
}

// ---------------- pass 3: bucket -> CSR esrc (writes localized per block) ----------------
__global__ void k_p3_scatter(const int* __restrict__ bcursor, const int* __restrict__ ebuf,
                             const int* __restrict__ rowstart, int* __restrict__ esrc) {
    __shared__ int lcur[BWID];
    int b = blockIdx.x;
    int tid = threadIdx.x;
    int node0 = b * BWID;
    for (int i = tid; i < BWID; i += 256) lcur[i] = rowstart[node0 + i];
    __syncthreads();
    int size = bcursor[b];
    if (size > BCAP) size = BCAP;
    const int* eb = ebuf + b * BCAP;
    for (int k = tid; k < size; k += 256) {
        int v = eb[k];
        int local = v >> 18;
        int pos = atomicAdd(&lcur[local], 1);
        esrc[pos] = v & 0x3FFFF;
    }
}

// ---------------- dense matmul: hws[n,32] = (X[n,K] @ W[K,32]) * inv_sqrt[n] ----------------
template <int K>
__global__ void k_mm(const float* __restrict__ X, const float* __restrict__ W,
                     const float* __restrict__ inv_sqrt, float* __restrict__ Y) {
    __shared__ float4 sW[K * 8];   // sW[k*8+q] = W[k][4q..4q+3]
    int tid = threadIdx.x;
    for (int i = tid; i < K * 8; i += 256) sW[i] = ((const float4*)W)[i];
    __syncthreads();
    int row = blockIdx.x * 256 + tid;
    if (row >= NN) return;
    float s = inv_sqrt[row];
    const float4* xp = (const float4*)(X + (size_t)row * K);
    float4 acc[8];
#pragma unroll
    for (int q = 0; q < 8; q++) acc[q] = make_float4(0.f, 0.f, 0.f, 0.f);
#pragma unroll 2
    for (int k4 = 0; k4 < K / 4; k4++) {
        float4 xv = xp[k4];
        const float4* wk = &sW[k4 * 32];
#pragma unroll
        for (int kk = 0; kk < 4; kk++) {
            float xs = (kk == 0) ? xv.x : (kk == 1) ? xv.y : (kk == 2) ? xv.z : xv.w;
#pragma unroll
            for (int q = 0; q < 8; q++) {
                float4 w = wk[kk * 8 + q];
                acc[q].x = fmaf(xs, w.x, acc[q].x);
                acc[q].y = fmaf(xs, w.y, acc[q].y);
                acc[q].z = fmaf(xs, w.z, acc[q].z);
                acc[q].w = fmaf(xs, w.w, acc[q].w);
            }
        }
    }
    float4* yp = (float4*)(Y + (size_t)row * 32);
#pragma unroll
    for (int q = 0; q < 8; q++) {
        float4 v = acc[q];
        v.x *= s; v.y *= s; v.z *= s; v.w *= s;
        yp[q] = v;
    }
}

// ---------------- gather-aggregate, 8-wide ILP, 32 channels/node ----------------
__global__ void k_aggr(const int* __restrict__ rowstart, const int* __restrict__ esrc,
                       const float* __restrict__ hws, const float* __restrict__ inv_sqrt,
                       const float* __restrict__ b, float* __restrict__ xout) {
    int t = blockIdx.x * 256 + threadIdx.x;
    int n = t >> 5, c = t & 31;
    if (n >= NN) return;
    int e0 = rowstart[n], e1 = rowstart[n + 1];
    float a[8];
    a[0] = hws[(size_t)n * 32 + c];
#pragma unroll
    for (int k = 1; k < 8; k++) a[k] = 0.0f;
    for (int e = e0; e < e1; e += 8) {
        int ss[8];
#pragma unroll
        for (int k = 0; k < 8; k++) ss[k] = esrc[(e + k < e1) ? e + k : e];
        float vv[8];
#pragma unroll
        for (int k = 0; k < 8; k++) vv[k] = hws[(size_t)ss[k] * 32 + c];
        a[0] += vv[0];
#pragma unroll
        for (int k = 1; k < 8; k++) a[k] += (e + k < e1) ? vv[k] : 0.0f;
    }
    float acc = ((a[0] + a[1]) + (a[2] + a[3])) + ((a[4] + a[5]) + (a[6] + a[7]));
    xout[t] = tanhf(fmaf(acc, inv_sqrt[n], b[c]));
}

// layer 4: hws4[n] = (x3[n,:] . W4) * inv_sqrt[n]
__global__ void k_mm4(const float* __restrict__ x3, const float* __restrict__ W4,
                      const float* __restrict__ inv_sqrt, float* __restrict__ hws4) {
    int n = blockIdx.x * 256 + threadIdx.x;
    if (n >= NN) return;
    const float4* xr = (const float4*)(x3 + (size_t)n * 32);
    float acc = 0.0f;
#pragma unroll
    for (int q = 0; q < 8; q++) {
        float4 v = xr[q];
        acc = fmaf(v.x, W4[q * 4 + 0], acc);
        acc = fmaf(v.y, W4[q * 4 + 1], acc);
        acc = fmaf(v.z, W4[q * 4 + 2], acc);
        acc = fmaf(v.w, W4[q * 4 + 3], acc);
    }
    hws4[n] = acc * inv_sqrt[n];
}

// layer-4 aggregation (1 channel), 8-wide ILP
__global__ void k_aggr1(const int* __restrict__ rowstart, const int* __restrict__ esrc,
                        const float* __restrict__ hws4, const float* __restrict__ inv_sqrt,
                        const float* __restrict__ b4, float* __restrict__ x4) {
    int n = blockIdx.x * 256 + threadIdx.x;
    if (n >= NN) return;
    int e0 = rowstart[n], e1 = rowstart[n + 1];
    float a[8];
    a[0] = hws4[n];
#pragma unroll
    for (int k = 1; k < 8; k++) a[k] = 0.0f;
    for (int e = e0; e < e1; e += 8) {
        int ss[8];
#pragma unroll
        for (int k = 0; k < 8; k++) ss[k] = esrc[(e + k < e1) ? e + k : e];
        float vv[8];
#pragma unroll
        for (int k = 0; k < 8; k++) vv[k] = hws4[ss[k]];
        a[0] += vv[0];
#pragma unroll
        for (int k = 1; k < 8; k++) a[k] += (e + k < e1) ? vv[k] : 0.0f;
    }
    float acc = ((a[0] + a[1]) + (a[2] + a[3])) + ((a[4] + a[5]) + (a[6] + a[7]));
    x4[n] = tanhf(fmaf(acc, inv_sqrt[n], b4[0]));
}

// ---------------- graph boundaries from sorted batch (no atomics) ----------------
// starts[g] = first node index with batch[n] >= g; starts[NG] = NN
__global__ void k_gbounds(const int* __restrict__ batch, int* __restrict__ starts) {
    int n = blockIdx.x * 256 + threadIdx.x;
    if (n >= NN) return;
    int bn = batch[n];
    int bp = (n == 0) ? -1 : batch[n - 1];
    for (int g = bp + 1; g <= bn; g++) starts[g] = n;
    if (n == NN - 1)
        for (int g = bn + 1; g <= NG; g++) starts[g] = NN;
}

__global__ void k_sortpool(const int* __restrict__ starts,
                           const float* __restrict__ x1, const float* __restrict__ x2,
                           const float* __restrict__ x3, const float* __restrict__ x4,
                           float* __restrict__ pooled) {
    __shared__ float keys[1024];
    __shared__ int sel[KSEL];
    int g = blockIdx.x;
    int tid = threadIdx.x;
    int start = starts[g];
    int cnt = starts[g + 1] - start;
    if (cnt > 1024) cnt = 1024;
    for (int i = tid; i < cnt; i += 256) keys[i] = x4[start + i];
    __syncthreads();
    for (int i = tid; i < cnt; i += 256) {
        float ki = keys[i];
        int rank = 0;
        for (int j = 0; j < cnt; j++) {
            float kj = keys[j];
            rank += (kj > ki) || (kj == ki && j < i);  // stable desc, matches lexsort
        }
        if (rank < KSEL) sel[rank] = start + i;
    }
    __syncthreads();
    int selcnt = cnt < KSEL ? cnt : KSEL;
    for (int t = tid; t < KSEL * CCAT; t += 256) {
        int r = t / CCAT, ch = t - r * CCAT;
        float v = 0.0f;
        if (r < selcnt) {
            int node = sel[r];
            if (ch < 32)      v = x1[(size_t)node * 32 + ch];
            else if (ch < 64) v = x2[(size_t)node * 32 + ch - 32];
            else if (ch < 96) v = x3[(size_t)node * 32 + ch - 64];
            else              v = x4[node];
        }
        pooled[g * (KSEL * CCAT) + t] = v;
    }
}

// ---------------- CNN + MLP head, one block per graph ----------------
__global__ void k_head(const float* __restrict__ pooled,
                       const float* __restrict__ w5, const float* __restrict__ b5,
                       const float* __restrict__ w6, const float* __restrict__ b6,
                       const float* __restrict__ fw1, const float* __restrict__ fb1,
                       const float* __restrict__ fw2, const float* __restrict__ fb2,
                       float* __restrict__ out) {
    __shared__ float sP[KSEL * CCAT];
    __shared__ float s5[16 * 30];
    __shared__ float smp[16 * 15];
    __shared__ float sz[352];
    __shared__ float sh[128];
    __shared__ float sl[10];
    int g = blockIdx.x;
    int tid = threadIdx.x;
    for (int i = tid; i < KSEL * CCAT; i += 256) sP[i] = pooled[g * (KSEL * CCAT) + i];
    __syncthreads();
    for (int t = tid; t < 16 * 30; t += 256) {
        int c = t / 30, j = t - c * 30;
        float acc = b5[c];
        for (int i = 0; i < CCAT; i++) acc = fmaf(sP[j * CCAT + i], w5[c * CCAT + i], acc);
        s5[c * 30 + j] = fmaxf(acc, 0.0f);
    }
    __syncthreads();
    for (int t = tid; t < 16 * 15; t += 256) {
        int c = t / 15, j = t - c * 15;
        smp[t] = fmaxf(s5[c * 30 + 2 * j], s5[c * 30 + 2 * j + 1]);
    }
    __syncthreads();
    for (int t = tid; t < 32 * 11; t += 256) {
        int c = t / 11, j = t - c * 11;
        float acc = b6[c];
        for (int ci = 0; ci < 16; ci++) {
#pragma unroll
            for (int k = 0; k < 5; k++)
                acc = fmaf(smp[ci * 15 + j + k], w6[(c * 16 + ci) * 5 + k], acc);
        }
        sz[t] = fmaxf(acc, 0.0f);
    }
    __syncthreads();
    if (tid < 128) {
        float acc = fb1[tid];
        for (int i = 0; i < 352; i++) acc = fmaf(sz[i], fw1[i * 128 + tid], acc);
        sh[tid] = fmaxf(acc, 0.0f);
    }
    __syncthreads();
    if (tid < 10) {
        float acc = fb2[tid];
        for (int i = 0; i < 128; i++) acc = fmaf(sh[i], fw2[i * 10 + tid], acc);
        sl[tid] = acc;
    }
    __syncthreads();
    if (tid < 10) {
        float m = -1e30f;
        for (int i = 0; i < 10; i++) m = fmaxf(m, sl[i]);
        float ssum = 0.0f;
        for (int i = 0; i < 10; i++) ssum += expf(sl[i] - m);
        out[g * 10 + tid] = sl[tid] - m - logf(ssum);
    }
}

extern "C" void kernel_launch(void* const* d_in, const int* in_sizes, int n_in,
                              void* d_out, int out_size, void* d_ws, size_t ws_size,
                              hipStream_t stream) {
    const float* x   = (const float*)d_in[0];
    const int*   ei  = (const int*)d_in[1];
    const int*   bat = (const int*)d_in[2];
    const float* W1  = (const float*)d_in[3];
    const float* b1  = (const float*)d_in[4];
    const float* W2  = (const float*)d_in[5];
    const float* b2  = (const float*)d_in[6];
    const float* W3  = (const float*)d_in[7];
    const float* b3  = (const float*)d_in[8];
    const float* W4  = (const float*)d_in[9];
    const float* b4  = (const float*)d_in[10];
    const float* w5  = (const float*)d_in[11];
    const float* b5  = (const float*)d_in[12];
    const float* w6  = (const float*)d_in[13];
    const float* b6  = (const float*)d_in[14];
    const float* fw1 = (const float*)d_in[15];
    const float* fb1 = (const float*)d_in[16];
    const float* fw2 = (const float*)d_in[17];
    const float* fb2 = (const float*)d_in[18];
    float* out = (float*)d_out;

    float* ws = (float*)d_ws;
    float* inv_sqrt = ws;                          // NN
    float* hws      = inv_sqrt + NN;               // NN*32 (also hws4 in first NN)
    float* x1       = hws + (size_t)NN * 32;       // NN*32
    float* x2       = x1 + (size_t)NN * 32;        // NN*32
    float* x3       = x2 + (size_t)NN * 32;        // NN*32
    float* x4       = x3 + (size_t)NN * 32;        // NN
    float* pooled   = x4 + NN;                     // NG*KSEL*CCAT
    int* rowcnt     = (int*)(pooled + NG * KSEL * CCAT);  // NPAD
    int* rowstart   = rowcnt + NPAD;               // NPAD
    int* esrc       = rowstart + NPAD;             // NE
    int* bcursor    = esrc + NE;                   // NB (pad to 512)
    int* bsums      = bcursor + 512;               // 256
    int* gstarts    = bsums + 256;                 // NG+1 (pad to 1024)
    int* ebuf       = (int*)x3;                    // NB*BCAP ints (16 MB), dead before x3 written

    const int TB = 256;
    int gN  = (NN + TB - 1) / TB;
    int gNC = (NN * 32 + TB - 1) / TB;

    // ---- CSR build via bucketed partition ----
    hipMemsetAsync(bcursor, 0, 512 * sizeof(int), stream);
    hipMemsetAsync(rowcnt, 0, NPAD * sizeof(int), stream);
    k_p1_partition<<<P1_BLKS, TB, 0, stream>>>(ei, bcursor, ebuf);
    k_p2_count<<<NB, TB, 0, stream>>>(bcursor, ebuf, rowcnt, inv_sqrt);
    k_scanA<<<SCAN_BLKS, 1024, 0, stream>>>(rowcnt, rowstart, bsums);
    k_scanB<<<1, 256, 0, stream>>>(bsums);
    k_scanC<<<SCAN_BLKS, 1024, 0, stream>>>(rowstart, bsums);
    k_p3_scatter<<<NB, TB, 0, stream>>>(bcursor, ebuf, rowstart, esrc);

    // ---- graph boundaries (sorted batch -> no atomics) ----
    k_gbounds<<<gN, TB, 0, stream>>>(bat, gstarts);

    // ---- GCN layers ----
    k_mm<128><<<gN, TB, 0, stream>>>(x, W1, inv_sqrt, hws);
    k_aggr<<<gNC, TB, 0, stream>>>(rowstart, esrc, hws, inv_sqrt, b1, x1);
    k_mm<32><<<gN, TB, 0, stream>>>(x1, W2, inv_sqrt, hws);
    k_aggr<<<gNC, TB, 0, stream>>>(rowstart, esrc, hws, inv_sqrt, b2, x2);
    k_mm<32><<<gN, TB, 0, stream>>>(x2, W3, inv_sqrt, hws);
    k_aggr<<<gNC, TB, 0, stream>>>(rowstart, esrc, hws, inv_sqrt, b3, x3);
    k_mm4<<<gN, TB, 0, stream>>>(x3, W4, inv_sqrt, hws);
    k_aggr1<<<gN, TB, 0, stream>>>(rowstart, esrc, hws, inv_sqrt, b4, x4);

    // ---- sort-pool + head ----
    k_sortpool<<<NG, TB, 0, stream>>>(gstarts, x1, x2, x3, x4, pooled);
    k_head<<<NG, TB, 0, stream>>>(pooled, w5, b5, w6, b6, fw1, fb1, fw2, fb2, out);
}